// Round 10
// baseline (341.619 us; speedup 1.0000x reference)
//
#include <hip/hip_runtime.h>
#include <math.h>

#define T_DIM 4096
#define D_DIM 256
#define K_NUM 1024
#define B_NUM 16
#define N_TOT (B_NUM * T_DIM)   // 65536
#define EPS_FLAG 0.25f          // fp16 gap err std ~0.02 + key-quant -> ~10 sigma

typedef float f32x4 __attribute__((ext_vector_type(4)));
typedef _Float16 half8 __attribute__((ext_vector_type(8)));

// ---------------- ws layout (bytes) ----------------
#define WS_FLAGCNT 0
#define WS_LOSS 4
#define WS_DONE 8
#define WS_HIST 64
#define WS_E2 4352
#define WS_QIDX 8704            // 256 KB
#define WS_FLAGLIST 270848      // 256 KB (legacy path only)
#define WS_BESTD 532992         // 256 KB (legacy path only)
#define WS_ESWZ 795136          // 512 KB: fp16 embed, fragment-swizzled
#define WS_ET4 1319424          // 1 MB: fp32 embed transposed [dd4][c] as float4
#define WS_XROWS_ET 2368000     // xrows (legacy) when eT4 present
#define WS_XROWS_NOET 1319424   // xrows (legacy) when ws too small for eT4

__device__ inline unsigned umin_(unsigned a, unsigned b) { return a < b ? a : b; }
__device__ inline unsigned umax_(unsigned a, unsigned b) { return a > b ? a : b; }

// ---------------- kernel: ws zero + |e_k|^2 + fp16 fragment-swizzled embed + eT4 ----------------
__global__ __launch_bounds__(256) void prep_kernel(const float* __restrict__ embed,
                                                   unsigned char* __restrict__ eswz,
                                                   float* __restrict__ e2,
                                                   float4* __restrict__ eT4, int useET,
                                                   int* __restrict__ wszero) {
    const int tid = threadIdx.x;
    if (blockIdx.x == 0) {
        #pragma unroll
        for (int i = tid; i < 1040; i += 256) wszero[i] = 0;   // flagcnt/loss/done/hist
    }
    const int col = blockIdx.x * 8 + (tid >> 5);
    const int c = tid & 31;
    const float* src = embed + (size_t)col * D_DIM + c * 8;
    half8 h;
    float f[8];
    float s = 0.f;
    #pragma unroll
    for (int j = 0; j < 8; ++j) {
        float v = src[j];
        f[j] = v;
        h[j] = (_Float16)v;
        s = fmaf(v, v, s);
    }
    const int g = col >> 4;
    const int k = c >> 2;
    const int l = ((c & 3) << 4) | (col & 15);
    *(half8*)(eswz + (size_t)g * 8192 + k * 1024 + l * 16) = h;
    if (useET) {
        float4 a = {f[0], f[1], f[2], f[3]};
        float4 b = {f[4], f[5], f[6], f[7]};
        eT4[(size_t)(c * 2 + 0) * K_NUM + col] = a;
        eT4[(size_t)(c * 2 + 1) * K_NUM + col] = b;
    }
    #pragma unroll
    for (int off = 16; off; off >>= 1) s += __shfl_down(s, off);
    if ((tid & 31) == 0) e2[col] = s;
}

// phase p = 0..63: cols p*16+(l&15); B frag addr = p*8192 + k*1024 + l*16
#define LOADB(BUF, P) do {                                                        \
    const unsigned char* _bp = eswz + (size_t)(P) * 8192 + (size_t)(l * 16);      \
    _Pragma("unroll")                                                             \
    for (int _k = 0; _k < 8; ++_k) BUF[_k] = *(const half8*)(_bp + _k * 1024);    \
} while (0)

// minimize d = (e2 - 2 dot) + 2048 > 0; key = (bits(d)&~63)|tag, track min/2nd-min (r3/r7-proven)
#define PHASE(BUF, P) do {                                                                     \
    const float _bias = fmaf(e2s[(P) * 16 + (l & 15)], -0.5f, -1024.f);                        \
    f32x4 c0e = {_bias, _bias, _bias, _bias};                                                  \
    f32x4 c1e = {_bias, _bias, _bias, _bias};                                                  \
    f32x4 c0o = {0.f, 0.f, 0.f, 0.f};                                                          \
    f32x4 c1o = {0.f, 0.f, 0.f, 0.f};                                                          \
    c0e = __builtin_amdgcn_mfma_f32_16x16x32_f16(Ah[0][0], BUF[0], c0e, 0, 0, 0);              \
    c1e = __builtin_amdgcn_mfma_f32_16x16x32_f16(Ah[1][0], BUF[0], c1e, 0, 0, 0);              \
    c0o = __builtin_amdgcn_mfma_f32_16x16x32_f16(Ah[0][1], BUF[1], c0o, 0, 0, 0);              \
    c1o = __builtin_amdgcn_mfma_f32_16x16x32_f16(Ah[1][1], BUF[1], c1o, 0, 0, 0);              \
    c0e = __builtin_amdgcn_mfma_f32_16x16x32_f16(Ah[0][2], BUF[2], c0e, 0, 0, 0);              \
    c1e = __builtin_amdgcn_mfma_f32_16x16x32_f16(Ah[1][2], BUF[2], c1e, 0, 0, 0);              \
    c0o = __builtin_amdgcn_mfma_f32_16x16x32_f16(Ah[0][3], BUF[3], c0o, 0, 0, 0);              \
    c1o = __builtin_amdgcn_mfma_f32_16x16x32_f16(Ah[1][3], BUF[3], c1o, 0, 0, 0);              \
    c0e = __builtin_amdgcn_mfma_f32_16x16x32_f16(Ah[0][4], BUF[4], c0e, 0, 0, 0);              \
    c1e = __builtin_amdgcn_mfma_f32_16x16x32_f16(Ah[1][4], BUF[4], c1e, 0, 0, 0);              \
    c0o = __builtin_amdgcn_mfma_f32_16x16x32_f16(Ah[0][5], BUF[5], c0o, 0, 0, 0);              \
    c1o = __builtin_amdgcn_mfma_f32_16x16x32_f16(Ah[1][5], BUF[5], c1o, 0, 0, 0);              \
    c0e = __builtin_amdgcn_mfma_f32_16x16x32_f16(Ah[0][6], BUF[6], c0e, 0, 0, 0);              \
    c1e = __builtin_amdgcn_mfma_f32_16x16x32_f16(Ah[1][6], BUF[6], c1e, 0, 0, 0);              \
    c0o = __builtin_amdgcn_mfma_f32_16x16x32_f16(Ah[0][7], BUF[7], c0o, 0, 0, 0);              \
    c1o = __builtin_amdgcn_mfma_f32_16x16x32_f16(Ah[1][7], BUF[7], c1o, 0, 0, 0);              \
    const unsigned _tag = (unsigned)(P);                                                       \
    _Pragma("unroll")                                                                          \
    for (int _r = 0; _r < 4; ++_r) {                                                           \
        float d0v = (c0e[_r] + c0o[_r]) * -2.f;                                                \
        float d1v = (c1e[_r] + c1o[_r]) * -2.f;                                                \
        unsigned k0 = (__float_as_uint(d0v) & 0xFFFFFFC0u) | _tag;                             \
        unsigned k1 = (__float_as_uint(d1v) & 0xFFFFFFC0u) | _tag;                             \
        unsigned m0 = umax_(bestk[_r], k0);                                                    \
        bestk[_r] = umin_(bestk[_r], k0);                                                      \
        seck[_r] = umin_(seck[_r], m0);                                                        \
        unsigned m1 = umax_(bestk[4 + _r], k1);                                                \
        bestk[4 + _r] = umin_(bestk[4 + _r], k1);                                              \
        seck[4 + _r] = umin_(seck[4 + _r], m1);                                                \
    }                                                                                          \
} while (0)

// ---------------- kernel: fp16 MFMA distance + fused exact re-resolve + z_q/hist/loss/finalize ----
// 512 blocks x 256 thr (r3/r7-proven config). Block: 128 rows x 1024 cols; wave: 32 rows.
// useET path: block re-resolves its OWN flagged rows exactly (eT4, coalesced) BEFORE the
// z_q gather -> no cleanup kernel, no patch writes. Last block finalizes.
__global__ __launch_bounds__(256, 2) void argmin_mfma_kernel(
    const float* __restrict__ x, const unsigned char* __restrict__ eswz,
    const float* __restrict__ e2, const float* __restrict__ embed,
    const float4* __restrict__ eT4, int useET,
    int* __restrict__ qidx, int* __restrict__ flagcnt, int* __restrict__ flaglist,
    float* __restrict__ bestd, float* __restrict__ xrows,
    float* __restrict__ out, int* __restrict__ hist,
    float* __restrict__ loss_sum, int cap, int* __restrict__ donecnt)
{
    __shared__ float e2s[K_NUM];
    __shared__ __align__(16) float tile[64 * 128];   // 32 KB z_q staging
    __shared__ int   qid_lds[128];
    __shared__ int   lrows[128];      // block-local rloc of flagged rows
    __shared__ float lbest[128];
    __shared__ __align__(16) float xs[256];
    __shared__ float rv[256];
    __shared__ int   rix[256];
    __shared__ int   lcnt;
    __shared__ int   gbase;
    __shared__ int   amlast;

    const int tid = threadIdx.x;
    const int w = tid >> 6;
    const int l = tid & 63;
    const int rb = blockIdx.x * 128;
    const int b = rb >> 12;
    const float* xb = x + (size_t)b * (D_DIM * T_DIM);
    if (tid == 0) lcnt = 0;

    half8 B0[8], B1[8];
    LOADB(B0, 0);                               // in flight during A conversion

    for (int i = tid; i < K_NUM; i += 256) e2s[i] = e2[i];

    // ---- load + convert A fragments (fp16) + exact |x|^2 per row ----
    half8 Ah[2][8];
    float x2v[2];
    #pragma unroll
    for (int f = 0; f < 2; ++f) {
        const int row = rb + w * 32 + f * 16 + (l & 15);
        const int t = row & (T_DIM - 1);
        const float* xp = xb + t;
        float s2 = 0.f;
        #pragma unroll
        for (int k = 0; k < 8; ++k) {
            const int d0 = k * 32 + ((l >> 4) << 3);
            half8 h;
            #pragma unroll
            for (int j = 0; j < 8; ++j) {
                float v = xp[(size_t)(d0 + j) * T_DIM];
                h[j] = (_Float16)v;
                s2 = fmaf(v, v, s2);
            }
            Ah[f][k] = h;
        }
        x2v[f] = s2;
    }
    #pragma unroll
    for (int f = 0; f < 2; ++f) {   // full 256-dim |x|^2 across the 4 replica lanes
        x2v[f] += __shfl_xor(x2v[f], 16);
        x2v[f] += __shfl_xor(x2v[f], 32);
    }
    __syncthreads();   // e2s + lcnt ready

    unsigned bestk[8], seck[8];
    #pragma unroll
    for (int s = 0; s < 8; ++s) { bestk[s] = 0xFFFFFFFFu; seck[s] = 0xFFFFFFFFu; }

    // ---- barrier-free main loop: 64 phases, register double-buffer (r3-proven) ----
    for (int pp = 0; pp < 31; ++pp) {
        LOADB(B1, 2 * pp + 1);
        PHASE(B0, 2 * pp);
        LOADB(B0, 2 * pp + 2);
        PHASE(B1, 2 * pp + 1);
    }
    LOADB(B1, 63);
    PHASE(B0, 62);
    PHASE(B1, 63);

    // ---- merge top-2 across the 16 lanes sharing each row; emit qidx/hist/flag/loss ----
    float lossw = 0.f;
    #pragma unroll
    for (int slot = 0; slot < 8; ++slot) {
        float bv = __uint_as_float(bestk[slot] & 0xFFFFFFC0u) - 2048.f;
        float sv = __uint_as_float(seck[slot] & 0xFFFFFFC0u) - 2048.f;
        int bi = (int)(bestk[slot] & 63u) * 16 + (l & 15);
        #pragma unroll
        for (int d = 1; d < 16; d <<= 1) {
            float ob = __shfl_xor(bv, d);
            int   oi = __shfl_xor(bi, d);
            float os = __shfl_xor(sv, d);
            bool take = (ob < bv) || (ob == bv && oi < bi);
            float loser = take ? bv : ob;
            bv = take ? ob : bv;
            bi = take ? oi : bi;
            sv = fminf(fminf(sv, os), loser);
        }
        const int srcl = ((l >> 4) << 2) + (slot & 3);
        const float x2r = __shfl(x2v[slot >> 2], srcl);
        if ((l & 15) == 0) {
            const int rloc = w * 32 + (slot >> 2) * 16 + (l >> 4) * 4 + (slot & 3);
            qidx[rb + rloc] = bi;
            qid_lds[rloc] = bi;
            atomicAdd(&hist[bi], 1);
            lossw += bv + x2r;   // approx d2 + exact |x|^2 (re-resolve patches flagged)
            if (sv - bv < EPS_FLAG) {
                int lp = atomicAdd(&lcnt, 1);
                lrows[lp] = rloc;
                lbest[lp] = bv;
            }
        }
    }
    lossw += __shfl_down(lossw, 16);
    lossw += __shfl_down(lossw, 32);
    if (l == 0) atomicAdd(loss_sum, lossw);

    __syncthreads();
    const int nloc = lcnt;

    if (useET) {
        // ---- fused exact fp32 re-resolve of this block's flagged rows (coalesced eT4) ----
        for (int i = 0; i < nloc; ++i) {
            const int rloc = lrows[i];
            const int row = rb + rloc;
            const int t = row & (T_DIM - 1);
            xs[tid] = xb[(size_t)tid * T_DIM + t];   // exact x row (cache-hot)
            __syncthreads();
            float acc4[4] = {0.f, 0.f, 0.f, 0.f};
            for (int dd4 = 0; dd4 < 64; ++dd4) {
                const float4 xv = *(const float4*)&xs[dd4 * 4];
                #pragma unroll
                for (int q = 0; q < 4; ++q) {
                    const float4 ev = eT4[(size_t)dd4 * K_NUM + q * 256 + tid];
                    acc4[q] = fmaf(ev.x, xv.x, acc4[q]);
                    acc4[q] = fmaf(ev.y, xv.y, acc4[q]);
                    acc4[q] = fmaf(ev.z, xv.z, acc4[q]);
                    acc4[q] = fmaf(ev.w, xv.w, acc4[q]);
                }
            }
            float bvv = 3.4e38f; int bii = 0x7FFFFFFF;
            #pragma unroll
            for (int q = 0; q < 4; ++q) {
                const int c = q * 256 + tid;
                const float s = fmaf(-2.f, acc4[q], e2s[c]);
                if (s < bvv || (s == bvv && c < bii)) { bvv = s; bii = c; }
            }
            rv[tid] = bvv; rix[tid] = bii;
            __syncthreads();
            for (int off = 128; off; off >>= 1) {
                if (tid < off) {
                    const float ov = rv[tid + off]; const int oi = rix[tid + off];
                    if (ov < rv[tid] || (ov == rv[tid] && oi < rix[tid])) {
                        rv[tid] = ov; rix[tid] = oi;
                    }
                }
                __syncthreads();
            }
            if (tid == 0) {
                const int mi = rix[0];
                const int old = qid_lds[rloc];
                if (mi != old) {
                    qid_lds[rloc] = mi;
                    qidx[row] = mi;
                    atomicAdd(&hist[mi], 1);
                    atomicAdd(&hist[old], -1);
                }
                atomicAdd(loss_sum, rv[0] - lbest[i]);   // exact - approx
            }
            __syncthreads();
        }
    } else {
        // ---- legacy epilogue a: compact x-row copies for flagged rows ----
        if (tid == 0) gbase = nloc ? atomicAdd(flagcnt, nloc) : 0;
        __syncthreads();
        for (int i = w; i < nloc; i += 4) {
            const int row = rb + lrows[i];
            const int p = gbase + i;
            const bool have = (p < cap);
            if (have) {
                const float* xp = xb + (row & (T_DIM - 1));
                float4 vv;
                vv.x = xp[(size_t)(l * 4 + 0) * T_DIM];
                vv.y = xp[(size_t)(l * 4 + 1) * T_DIM];
                vv.z = xp[(size_t)(l * 4 + 2) * T_DIM];
                vv.w = xp[(size_t)(l * 4 + 3) * T_DIM];
                *(float4*)(xrows + (size_t)p * D_DIM + l * 4) = vv;
            }
            if (l == 0) {
                flaglist[p] = have ? row : (row | 0x80000000);
                bestd[p] = lbest[i];
            }
        }
    }

    // ---- epilogue b: fused z_q gather + coalesced write (tile [64 d][128 t]) ----
    const int t0 = rb & (T_DIM - 1);
    float* outb = out + (size_t)b * (D_DIM * T_DIM);
    for (int c = 0; c < 4; ++c) {
        const int d0 = c * 64;
        __syncthreads();                       // tile free; qid_lds final
        {
            const int r = tid & 127;
            const int half = tid >> 7;
            const int qi = qid_lds[r];
            const float4* ep = (const float4*)(embed + (size_t)qi * D_DIM + d0 + half * 32);
            #pragma unroll
            for (int i = 0; i < 8; ++i) {
                const float4 ev = ep[i];
                const int dl = half * 32 + i * 4;
                tile[(dl + 0) * 128 + r] = ev.x;
                tile[(dl + 1) * 128 + r] = ev.y;
                tile[(dl + 2) * 128 + r] = ev.z;
                tile[(dl + 3) * 128 + r] = ev.w;
            }
        }
        __syncthreads();
        #pragma unroll 4
        for (int j = 0; j < 32; ++j) {
            const int flat = j * 256 + tid;
            const int dl = flat >> 7;
            const int rr = flat & 127;
            outb[(size_t)(d0 + dl) * T_DIM + t0 + rr] = tile[dl * 128 + rr];
        }
    }

    if (useET) {
        // ---- fused finalize: last block computes entropy + writes scalar outputs ----
        __threadfence();
        if (tid == 0) {
            const int old = atomicAdd(donecnt, 1);
            amlast = (old == (int)gridDim.x - 1) ? 1 : 0;
        }
        __syncthreads();
        if (amlast) {
            float acc = 0.f;
            for (int i = tid; i < K_NUM; i += 256) {
                const int h = __hip_atomic_load(&hist[i], __ATOMIC_RELAXED,
                                                __HIP_MEMORY_SCOPE_AGENT);
                const float p = (float)h * (1.f / (float)N_TOT);
                acc += p * logf(p + 1e-10f);
            }
            #pragma unroll
            for (int off = 32; off; off >>= 1) acc += __shfl_down(acc, off);
            if ((tid & 63) == 0) rv[tid >> 6] = acc;
            __syncthreads();
            if (tid == 0) {
                const float H = -(rv[0] + rv[1] + rv[2] + rv[3]);
                const float L = __hip_atomic_load(loss_sum, __ATOMIC_RELAXED,
                                                  __HIP_MEMORY_SCOPE_AGENT);
                const size_t base = (size_t)N_TOT * D_DIM;   // 16777216
                out[base] = 1.25f * L * (1.f / 16777216.f);
                const float kld = (float)(6.931471805599453 * 4096.0);  // log(1024)*T
                #pragma unroll
                for (int i = 0; i < 16; ++i) out[base + 1 + i] = kld;
                out[base + 17] = expf(H);
            }
        }
    }
}

// ---------------- legacy kernel: exact re-resolve + finalize (launched only when !useET) ------
__global__ __launch_bounds__(256) void cleanup_kernel(
    const float* __restrict__ x, const float* __restrict__ xrows,
    const float* __restrict__ embed, const float* __restrict__ e2,
    const int* __restrict__ flagcnt, const int* __restrict__ flaglist,
    int* __restrict__ qidx, const float* __restrict__ bestd,
    float* __restrict__ loss_sum, float* __restrict__ out, int* __restrict__ hist,
    int* __restrict__ donecnt)
{
    __shared__ float xr[8][256];
    __shared__ float rvall[8][256];
    __shared__ int   rixall[8][256];
    __shared__ int   rowss[8];
    __shared__ int   amlast;
    const int tid = threadIdx.x;
    const int w = tid >> 6;
    int cnt = flagcnt[0];
    if (cnt > N_TOT) cnt = N_TOT;
    for (int base = blockIdx.x * 8; base < cnt; base += gridDim.x * 8) {
        const int nr = (cnt - base < 8) ? (cnt - base) : 8;
        __syncthreads();
        if (tid < 8) rowss[tid] = (tid < nr) ? flaglist[base + tid] : 0;
        __syncthreads();
        #pragma unroll
        for (int r = 0; r < 8; ++r) {
            float v = 0.f;
            if (r < nr) {
                const int fe = rowss[r];
                if (fe >= 0) {
                    v = xrows[(size_t)(base + r) * D_DIM + tid];
                } else {
                    const int row = fe & 0x7FFFFFFF;
                    v = x[(size_t)(row >> 12) * (D_DIM * T_DIM) + (size_t)tid * T_DIM
                          + (row & (T_DIM - 1))];
                }
            }
            xr[r][tid] = v;
        }
        __syncthreads();

        float bv[8]; int bix[8];
        #pragma unroll
        for (int r = 0; r < 8; ++r) { bv[r] = 3.4e38f; bix[r] = 0x7FFFFFFF; }
        for (int q = 0; q < 4; ++q) {
            const int c = q * 256 + tid;
            const float4* ep = (const float4*)(embed + (size_t)c * D_DIM);
            float acc[8];
            #pragma unroll
            for (int r = 0; r < 8; ++r) acc[r] = 0.f;
            #pragma unroll 8
            for (int dd = 0; dd < 64; ++dd) {
                const float4 ev = ep[dd];
                #pragma unroll
                for (int r = 0; r < 8; ++r) {
                    const float4 xv = *(const float4*)&xr[r][dd * 4];
                    acc[r] = fmaf(ev.x, xv.x, acc[r]);
                    acc[r] = fmaf(ev.y, xv.y, acc[r]);
                    acc[r] = fmaf(ev.z, xv.z, acc[r]);
                    acc[r] = fmaf(ev.w, xv.w, acc[r]);
                }
            }
            const float ec = e2[c];
            #pragma unroll
            for (int r = 0; r < 8; ++r) {
                const float s = fmaf(-2.f, acc[r], ec);
                if (s < bv[r] || (s == bv[r] && c < bix[r])) { bv[r] = s; bix[r] = c; }
            }
        }
        #pragma unroll
        for (int r = 0; r < 8; ++r) { rvall[r][tid] = bv[r]; rixall[r][tid] = bix[r]; }
        __syncthreads();
        const int ll = tid & 63;
        #pragma unroll
        for (int rr2 = 0; rr2 < 2; ++rr2) {
            const int r = w * 2 + rr2;
            float mv = 3.4e38f; int mi = 0x7FFFFFFF;
            #pragma unroll
            for (int j = 0; j < 4; ++j) {
                const float v = rvall[r][ll + j * 64];
                const int i2 = rixall[r][ll + j * 64];
                if (v < mv || (v == mv && i2 < mi)) { mv = v; mi = i2; }
            }
            #pragma unroll
            for (int d = 1; d < 64; d <<= 1) {
                const float ov = __shfl_xor(mv, d);
                const int   oi = __shfl_xor(mi, d);
                if (ov < mv || (ov == mv && oi < mi)) { mv = ov; mi = oi; }
            }
            if (r < nr) {
                const int row = rowss[r] & 0x7FFFFFFF;
                const int old = qidx[row];
                if (mi != old) {
                    const int b2 = row >> 12, t2 = row & (T_DIM - 1);
                    const float4 ev = *(const float4*)(embed + (size_t)mi * D_DIM + ll * 4);
                    float* op = out + (size_t)b2 * (D_DIM * T_DIM) + t2;
                    op[(size_t)(ll * 4 + 0) * T_DIM] = ev.x;
                    op[(size_t)(ll * 4 + 1) * T_DIM] = ev.y;
                    op[(size_t)(ll * 4 + 2) * T_DIM] = ev.z;
                    op[(size_t)(ll * 4 + 3) * T_DIM] = ev.w;
                    if (ll == 0) {
                        qidx[row] = mi;
                        atomicAdd(&hist[mi], 1);
                        atomicAdd(&hist[old], -1);
                    }
                }
                if (ll == 0) atomicAdd(loss_sum, mv - bestd[base + r]);
            }
        }
    }

    __threadfence();
    if (tid == 0) {
        const int old = atomicAdd(donecnt, 1);
        amlast = (old == (int)gridDim.x - 1) ? 1 : 0;
    }
    __syncthreads();
    if (amlast) {
        float acc = 0.f;
        for (int i = tid; i < K_NUM; i += 256) {
            const int h = __hip_atomic_load(&hist[i], __ATOMIC_RELAXED,
                                            __HIP_MEMORY_SCOPE_AGENT);
            const float p = (float)h * (1.f / (float)N_TOT);
            acc += p * logf(p + 1e-10f);
        }
        #pragma unroll
        for (int off = 32; off; off >>= 1) acc += __shfl_down(acc, off);
        __shared__ float ls[4];
        if ((tid & 63) == 0) ls[tid >> 6] = acc;
        __syncthreads();
        if (tid == 0) {
            const float H = -(ls[0] + ls[1] + ls[2] + ls[3]);
            const float L = __hip_atomic_load(loss_sum, __ATOMIC_RELAXED,
                                              __HIP_MEMORY_SCOPE_AGENT);
            const size_t base = (size_t)N_TOT * D_DIM;   // 16777216
            out[base] = 1.25f * L * (1.f / 16777216.f);
            const float kld = (float)(6.931471805599453 * 4096.0);  // log(1024)*T
            #pragma unroll
            for (int i = 0; i < 16; ++i) out[base + 1 + i] = kld;
            out[base + 17] = expf(H);
        }
    }
}

extern "C" void kernel_launch(void* const* d_in, const int* in_sizes, int n_in,
                              void* d_out, int out_size, void* d_ws, size_t ws_size,
                              hipStream_t stream)
{
    const float* x     = (const float*)d_in[0];   // (16, 256, 4096) f32
    const float* embed = (const float*)d_in[1];   // (1024, 256) f32
    float* out = (float*)d_out;

    char* ws = (char*)d_ws;
    int*   flagcnt  = (int*)(ws + WS_FLAGCNT);
    float* loss_sum = (float*)(ws + WS_LOSS);
    int*   donecnt  = (int*)(ws + WS_DONE);
    int*   hist     = (int*)(ws + WS_HIST);
    float* e2       = (float*)(ws + WS_E2);
    int*   qidx     = (int*)(ws + WS_QIDX);
    int*   flaglist = (int*)(ws + WS_FLAGLIST);
    float* bestd    = (float*)(ws + WS_BESTD);
    unsigned char* eswz = (unsigned char*)(ws + WS_ESWZ);
    float4* eT4     = (float4*)(ws + WS_ET4);

    const int useET = (ws_size >= (size_t)WS_ET4 + 1048576 + 2048) ? 1 : 0;
    const size_t xrows_off = useET ? (size_t)WS_XROWS_ET : (size_t)WS_XROWS_NOET;
    float* xrows = (float*)(ws + xrows_off);

    int cap = 0;
    if (ws_size > xrows_off + 1024) {
        size_t c = (ws_size - xrows_off) / 1024;
        cap = (c > (size_t)N_TOT) ? N_TOT : (int)c;
    }

    prep_kernel<<<128, 256, 0, stream>>>(embed, eswz, e2, eT4, useET, (int*)ws);
    argmin_mfma_kernel<<<N_TOT / 128, 256, 0, stream>>>(x, eswz, e2, embed, eT4, useET,
                                                        qidx, flagcnt, flaglist, bestd,
                                                        xrows, out, hist, loss_sum, cap,
                                                        donecnt);
    if (!useET) {
        cleanup_kernel<<<512, 256, 0, stream>>>(x, xrows, embed, e2, flagcnt, flaglist,
                                                qidx, bestd, loss_sum, out, hist, donecnt);
    }
}

// Round 11
// 263.722 us; speedup vs baseline: 1.2954x; 1.2954x over previous
//
#include <hip/hip_runtime.h>
#include <math.h>

#define T_DIM 4096
#define D_DIM 256
#define K_NUM 1024
#define B_NUM 16
#define N_TOT (B_NUM * T_DIM)   // 65536
#define EPS_FLAG 0.18f          // gap err: gaussian sigma~0.015 + key-quant <=0.031 -> ~10 sigma

typedef float f32x4 __attribute__((ext_vector_type(4)));
typedef _Float16 half8 __attribute__((ext_vector_type(8)));

// ---------------- ws layout (bytes) ----------------
#define WS_FLAGCNT 0
#define WS_LOSS 4
#define WS_DONE 8
#define WS_HIST 64
#define WS_E2 4352
#define WS_QIDX 8704            // 256 KB
#define WS_FLAGLIST 270848      // 256 KB
#define WS_BESTD 532992         // 256 KB (approx d2 per flag slot)
#define WS_ESWZ 795136          // 512 KB: fp16 embed, fragment-swizzled
#define WS_ET4 1319424          // 1 MB: fp32 embed transposed [dd4][c] as float4
#define WS_XROWS_ET 2368000     // xrows when eT4 present
#define WS_XROWS_NOET 1319424   // xrows when ws too small for eT4

__device__ inline unsigned umin_(unsigned a, unsigned b) { return a < b ? a : b; }
__device__ inline unsigned umax_(unsigned a, unsigned b) { return a > b ? a : b; }

// ---------------- kernel: ws zero + |e_k|^2 + fp16 fragment-swizzled embed + eT4 ----------------
// 128 blocks x 256 thr. thread -> (col = b*8 + t>>5, c = t&31) owns d = c*8..c*8+7.
// eswz slot: g=col>>4, k=c>>2, l=((c&3)<<4)|(col&15)  (B-fragment layout, verified)
// eT4: [dd4][codeword] float4 (codeword-major inner -> coalesced cleanup loads)
__global__ __launch_bounds__(256) void prep_kernel(const float* __restrict__ embed,
                                                   unsigned char* __restrict__ eswz,
                                                   float* __restrict__ e2,
                                                   float4* __restrict__ eT4, int useET,
                                                   int* __restrict__ wszero) {
    const int tid = threadIdx.x;
    if (blockIdx.x == 0) {
        #pragma unroll
        for (int i = tid; i < 1040; i += 256) wszero[i] = 0;   // flagcnt/loss/done/hist
    }
    const int col = blockIdx.x * 8 + (tid >> 5);
    const int c = tid & 31;
    const float* src = embed + (size_t)col * D_DIM + c * 8;
    half8 h;
    float f[8];
    float s = 0.f;
    #pragma unroll
    for (int j = 0; j < 8; ++j) {
        float v = src[j];
        f[j] = v;
        h[j] = (_Float16)v;
        s = fmaf(v, v, s);
    }
    const int g = col >> 4;
    const int k = c >> 2;
    const int l = ((c & 3) << 4) | (col & 15);
    *(half8*)(eswz + (size_t)g * 8192 + k * 1024 + l * 16) = h;
    if (useET) {
        float4 a = {f[0], f[1], f[2], f[3]};
        float4 b = {f[4], f[5], f[6], f[7]};
        eT4[(size_t)(c * 2 + 0) * K_NUM + col] = a;
        eT4[(size_t)(c * 2 + 1) * K_NUM + col] = b;
    }
    #pragma unroll
    for (int off = 16; off; off >>= 1) s += __shfl_down(s, off);
    if ((tid & 31) == 0) e2[col] = s;
}

// phase p = 0..63: cols p*16+(l&15); B frag addr = p*8192 + k*1024 + l*16
#define LOADB(BUF, P) do {                                                        \
    const unsigned char* _bp = eswz + (size_t)(P) * 8192 + (size_t)(l * 16);      \
    _Pragma("unroll")                                                             \
    for (int _k = 0; _k < 8; ++_k) BUF[_k] = *(const half8*)(_bp + _k * 1024);    \
} while (0)

#define PHASE(BUF, P) do {                                                                     \
    const float _bias = fmaf(e2s[(P) * 16 + (l & 15)], -0.5f, -1024.f);                        \
    f32x4 c0e = {_bias, _bias, _bias, _bias};                                                  \
    f32x4 c1e = {_bias, _bias, _bias, _bias};                                                  \
    f32x4 c0o = {0.f, 0.f, 0.f, 0.f};                                                          \
    f32x4 c1o = {0.f, 0.f, 0.f, 0.f};                                                          \
    c0e = __builtin_amdgcn_mfma_f32_16x16x32_f16(Ah[0][0], BUF[0], c0e, 0, 0, 0);              \
    c1e = __builtin_amdgcn_mfma_f32_16x16x32_f16(Ah[1][0], BUF[0], c1e, 0, 0, 0);              \
    c0o = __builtin_amdgcn_mfma_f32_16x16x32_f16(Ah[0][1], BUF[1], c0o, 0, 0, 0);              \
    c1o = __builtin_amdgcn_mfma_f32_16x16x32_f16(Ah[1][1], BUF[1], c1o, 0, 0, 0);              \
    c0e = __builtin_amdgcn_mfma_f32_16x16x32_f16(Ah[0][2], BUF[2], c0e, 0, 0, 0);              \
    c1e = __builtin_amdgcn_mfma_f32_16x16x32_f16(Ah[1][2], BUF[2], c1e, 0, 0, 0);              \
    c0o = __builtin_amdgcn_mfma_f32_16x16x32_f16(Ah[0][3], BUF[3], c0o, 0, 0, 0);              \
    c1o = __builtin_amdgcn_mfma_f32_16x16x32_f16(Ah[1][3], BUF[3], c1o, 0, 0, 0);              \
    c0e = __builtin_amdgcn_mfma_f32_16x16x32_f16(Ah[0][4], BUF[4], c0e, 0, 0, 0);              \
    c1e = __builtin_amdgcn_mfma_f32_16x16x32_f16(Ah[1][4], BUF[4], c1e, 0, 0, 0);              \
    c0o = __builtin_amdgcn_mfma_f32_16x16x32_f16(Ah[0][5], BUF[5], c0o, 0, 0, 0);              \
    c1o = __builtin_amdgcn_mfma_f32_16x16x32_f16(Ah[1][5], BUF[5], c1o, 0, 0, 0);              \
    c0e = __builtin_amdgcn_mfma_f32_16x16x32_f16(Ah[0][6], BUF[6], c0e, 0, 0, 0);              \
    c1e = __builtin_amdgcn_mfma_f32_16x16x32_f16(Ah[1][6], BUF[6], c1e, 0, 0, 0);              \
    c0o = __builtin_amdgcn_mfma_f32_16x16x32_f16(Ah[0][7], BUF[7], c0o, 0, 0, 0);              \
    c1o = __builtin_amdgcn_mfma_f32_16x16x32_f16(Ah[1][7], BUF[7], c1o, 0, 0, 0);              \
    const unsigned _tag = (unsigned)(P);                                                       \
    _Pragma("unroll")                                                                          \
    for (int _r = 0; _r < 4; ++_r) {                                                           \
        float d0v = (c0e[_r] + c0o[_r]) * -2.f;                                                \
        float d1v = (c1e[_r] + c1o[_r]) * -2.f;                                                \
        unsigned k0 = (__float_as_uint(d0v) & 0xFFFFFFC0u) | _tag;                             \
        unsigned k1 = (__float_as_uint(d1v) & 0xFFFFFFC0u) | _tag;                             \
        unsigned m0 = umax_(bestk[_r], k0);                                                    \
        bestk[_r] = umin_(bestk[_r], k0);                                                      \
        seck[_r] = umin_(seck[_r], m0);                                                        \
        unsigned m1 = umax_(bestk[4 + _r], k1);                                                \
        bestk[4 + _r] = umin_(bestk[4 + _r], k1);                                              \
        seck[4 + _r] = umin_(seck[4 + _r], m1);                                                \
    }                                                                                          \
} while (0)

// ---------------- kernel: fp16 MFMA distance, barrier-free loop, fused z_q/hist/loss ----------------
// 512 blocks x 256 thr. Block: 128 consecutive rows x all 1024 cols; wave: 32 rows.
// B frags read straight from L2-resident eswz into a 2-deep register double-buffer.
__global__ __launch_bounds__(256, 2) void argmin_mfma_kernel(
    const float* __restrict__ x, const unsigned char* __restrict__ eswz,
    const float* __restrict__ e2, const float* __restrict__ embed,
    int* __restrict__ qidx, int* __restrict__ flagcnt, int* __restrict__ flaglist,
    float* __restrict__ bestd, float* __restrict__ xrows,
    float* __restrict__ out, int* __restrict__ hist,
    float* __restrict__ loss_sum, int cap)
{
    __shared__ float e2s[K_NUM];
    __shared__ __align__(16) float tile[64 * 128];   // 32 KB z_q staging
    __shared__ int   qid_lds[128];
    __shared__ int   lrows[128];
    __shared__ float lbest[128];
    __shared__ int   lcnt;
    __shared__ int   gbase;

    const int tid = threadIdx.x;
    const int w = tid >> 6;
    const int l = tid & 63;
    const int rb = blockIdx.x * 128;
    const int b = rb >> 12;
    const float* xb = x + (size_t)b * (D_DIM * T_DIM);
    if (tid == 0) lcnt = 0;

    half8 B0[8], B1[8];
    LOADB(B0, 0);                               // in flight during A conversion

    for (int i = tid; i < K_NUM; i += 256) e2s[i] = e2[i];

    // ---- load + convert A fragments (fp16) + exact |x|^2 per row ----
    half8 Ah[2][8];
    float x2v[2];
    #pragma unroll
    for (int f = 0; f < 2; ++f) {
        const int row = rb + w * 32 + f * 16 + (l & 15);
        const int t = row & (T_DIM - 1);
        const float* xp = xb + t;
        float s2 = 0.f;
        #pragma unroll
        for (int k = 0; k < 8; ++k) {
            const int d0 = k * 32 + ((l >> 4) << 3);
            half8 h;
            #pragma unroll
            for (int j = 0; j < 8; ++j) {
                float v = xp[(size_t)(d0 + j) * T_DIM];
                h[j] = (_Float16)v;
                s2 = fmaf(v, v, s2);
            }
            Ah[f][k] = h;
        }
        x2v[f] = s2;
    }
    #pragma unroll
    for (int f = 0; f < 2; ++f) {   // full 256-dim |x|^2 across the 4 replica lanes
        x2v[f] += __shfl_xor(x2v[f], 16);
        x2v[f] += __shfl_xor(x2v[f], 32);
    }
    __syncthreads();   // e2s + lcnt ready

    unsigned bestk[8], seck[8];
    #pragma unroll
    for (int s = 0; s < 8; ++s) { bestk[s] = 0xFFFFFFFFu; seck[s] = 0xFFFFFFFFu; }

    // ---- barrier-free main loop: 64 phases, register double-buffer ----
    for (int pp = 0; pp < 31; ++pp) {
        LOADB(B1, 2 * pp + 1);
        PHASE(B0, 2 * pp);
        LOADB(B0, 2 * pp + 2);
        PHASE(B1, 2 * pp + 1);
    }
    LOADB(B1, 63);
    PHASE(B0, 62);
    PHASE(B1, 63);

    // ---- merge top-2 across the 16 lanes sharing each row; emit qidx/hist/flag/loss ----
    float lossw = 0.f;
    #pragma unroll
    for (int slot = 0; slot < 8; ++slot) {
        float bv = __uint_as_float(bestk[slot] & 0xFFFFFFC0u) - 2048.f;
        float sv = __uint_as_float(seck[slot] & 0xFFFFFFC0u) - 2048.f;
        int bi = (int)(bestk[slot] & 63u) * 16 + (l & 15);
        #pragma unroll
        for (int d = 1; d < 16; d <<= 1) {
            float ob = __shfl_xor(bv, d);
            int   oi = __shfl_xor(bi, d);
            float os = __shfl_xor(sv, d);
            bool take = (ob < bv) || (ob == bv && oi < bi);
            float loser = take ? bv : ob;
            bv = take ? ob : bv;
            bi = take ? oi : bi;
            sv = fminf(fminf(sv, os), loser);
        }
        const int srcl = ((l >> 4) << 2) + (slot & 3);
        const float x2r = __shfl(x2v[slot >> 2], srcl);
        if ((l & 15) == 0) {
            const int rloc = w * 32 + (slot >> 2) * 16 + (l >> 4) * 4 + (slot & 3);
            qidx[rb + rloc] = bi;
            qid_lds[rloc] = bi;
            atomicAdd(&hist[bi], 1);
            lossw += bv + x2r;   // approx d2 + exact |x|^2 (cleanup patches flagged)
            if (sv - bv < EPS_FLAG) {
                int lp = atomicAdd(&lcnt, 1);
                lrows[lp] = rb + rloc;
                lbest[lp] = bv;
            }
        }
    }
    lossw += __shfl_down(lossw, 16);
    lossw += __shfl_down(lossw, 32);
    if (l == 0) atomicAdd(loss_sum, lossw);

    // ---- epilogue a: compact x-row copies for flagged rows (reads are cache-hot) ----
    __syncthreads();
    const int nloc = lcnt;
    if (tid == 0) gbase = nloc ? atomicAdd(flagcnt, nloc) : 0;
    __syncthreads();
    for (int i = w; i < nloc; i += 4) {        // one wave per flagged row
        const int row = lrows[i];
        const int p = gbase + i;
        const bool have = (p < cap);
        if (have) {
            const float* xp = xb + (row & (T_DIM - 1));
            float4 vv;
            vv.x = xp[(size_t)(l * 4 + 0) * T_DIM];
            vv.y = xp[(size_t)(l * 4 + 1) * T_DIM];
            vv.z = xp[(size_t)(l * 4 + 2) * T_DIM];
            vv.w = xp[(size_t)(l * 4 + 3) * T_DIM];
            *(float4*)(xrows + (size_t)p * D_DIM + l * 4) = vv;
        }
        if (l == 0) {
            flaglist[p] = have ? row : (row | 0x80000000);
            bestd[p] = lbest[i];
        }
    }

    // ---- epilogue b: fused z_q gather + coalesced write (tile [64 d][128 t]) ----
    const int t0 = rb & (T_DIM - 1);
    float* outb = out + (size_t)b * (D_DIM * T_DIM);
    for (int c = 0; c < 4; ++c) {
        const int d0 = c * 64;
        __syncthreads();                       // tile free
        {
            const int r = tid & 127;
            const int half = tid >> 7;
            const int qi = qid_lds[r];
            const float4* ep = (const float4*)(embed + (size_t)qi * D_DIM + d0 + half * 32);
            #pragma unroll
            for (int i = 0; i < 8; ++i) {
                const float4 ev = ep[i];
                const int dl = half * 32 + i * 4;
                tile[(dl + 0) * 128 + r] = ev.x;
                tile[(dl + 1) * 128 + r] = ev.y;
                tile[(dl + 2) * 128 + r] = ev.z;
                tile[(dl + 3) * 128 + r] = ev.w;
            }
        }
        __syncthreads();
        #pragma unroll 4
        for (int j = 0; j < 32; ++j) {
            const int flat = j * 256 + tid;
            const int dl = flat >> 7;
            const int rr = flat & 127;
            outb[(size_t)(d0 + dl) * T_DIM + t0 + rr] = tile[dl * 128 + rr];
        }
    }
}

// ---------------- kernel: exact fp32 re-resolve (coalesced eT4) + fused finalize ----------------
// 8 rows/pass; per dd4: 4 coalesced ev float4 loads (issued together) + 8 LDS xv + 128 FMA.
__global__ __launch_bounds__(256) void cleanup_kernel(
    const float* __restrict__ x, const float* __restrict__ xrows,
    const float* __restrict__ embed, const float4* __restrict__ eT4, int useET,
    const float* __restrict__ e2,
    const int* __restrict__ flagcnt, const int* __restrict__ flaglist,
    int* __restrict__ qidx, const float* __restrict__ bestd,
    float* __restrict__ loss_sum, float* __restrict__ out, int* __restrict__ hist,
    int* __restrict__ donecnt)
{
    __shared__ float xr[8][256];
    __shared__ float rvall[8][256];
    __shared__ int   rixall[8][256];
    __shared__ int   rowss[8];
    __shared__ int   amlast;
    const int tid = threadIdx.x;
    const int w = tid >> 6;
    int cnt = flagcnt[0];
    if (cnt > N_TOT) cnt = N_TOT;
    for (int base = blockIdx.x * 8; base < cnt; base += gridDim.x * 8) {
        const int nr = (cnt - base < 8) ? (cnt - base) : 8;
        __syncthreads();
        if (tid < 8) rowss[tid] = (tid < nr) ? flaglist[base + tid] : 0;
        __syncthreads();
        #pragma unroll
        for (int r = 0; r < 8; ++r) {
            float v = 0.f;
            if (r < nr) {
                const int fe = rowss[r];
                if (fe >= 0) {
                    v = xrows[(size_t)(base + r) * D_DIM + tid];
                } else {   // slow path: no compact copy (cap overflow)
                    const int row = fe & 0x7FFFFFFF;
                    v = x[(size_t)(row >> 12) * (D_DIM * T_DIM) + (size_t)tid * T_DIM
                          + (row & (T_DIM - 1))];
                }
            }
            xr[r][tid] = v;
        }
        __syncthreads();

        float acc[4][8];
        #pragma unroll
        for (int q = 0; q < 4; ++q)
            #pragma unroll
            for (int r = 0; r < 8; ++r) acc[q][r] = 0.f;
        #pragma unroll 2
        for (int dd4 = 0; dd4 < 64; ++dd4) {
            float4 ev[4];
            #pragma unroll
            for (int q = 0; q < 4; ++q) {
                const int c = q * 256 + tid;
                ev[q] = useET ? eT4[(size_t)dd4 * K_NUM + c]
                              : *((const float4*)(embed + (size_t)c * D_DIM) + dd4);
            }
            float4 xv[8];
            #pragma unroll
            for (int r = 0; r < 8; ++r) xv[r] = *(const float4*)&xr[r][dd4 * 4];
            #pragma unroll
            for (int q = 0; q < 4; ++q) {
                #pragma unroll
                for (int r = 0; r < 8; ++r) {
                    acc[q][r] = fmaf(ev[q].x, xv[r].x, acc[q][r]);
                    acc[q][r] = fmaf(ev[q].y, xv[r].y, acc[q][r]);
                    acc[q][r] = fmaf(ev[q].z, xv[r].z, acc[q][r]);
                    acc[q][r] = fmaf(ev[q].w, xv[r].w, acc[q][r]);
                }
            }
        }
        float bv[8]; int bix[8];
        #pragma unroll
        for (int r = 0; r < 8; ++r) { bv[r] = 3.4e38f; bix[r] = 0x7FFFFFFF; }
        #pragma unroll
        for (int q = 0; q < 4; ++q) {
            const int c = q * 256 + tid;
            const float ec = e2[c];
            #pragma unroll
            for (int r = 0; r < 8; ++r) {
                const float s = fmaf(-2.f, acc[q][r], ec);
                if (s < bv[r] || (s == bv[r] && c < bix[r])) { bv[r] = s; bix[r] = c; }
            }
        }
        #pragma unroll
        for (int r = 0; r < 8; ++r) { rvall[r][tid] = bv[r]; rixall[r][tid] = bix[r]; }
        __syncthreads();
        const int ll = tid & 63;
        #pragma unroll
        for (int rr2 = 0; rr2 < 2; ++rr2) {
            const int r = w * 2 + rr2;
            float mv = 3.4e38f; int mi = 0x7FFFFFFF;
            #pragma unroll
            for (int j = 0; j < 4; ++j) {
                const float v = rvall[r][ll + j * 64];
                const int i2 = rixall[r][ll + j * 64];
                if (v < mv || (v == mv && i2 < mi)) { mv = v; mi = i2; }
            }
            #pragma unroll
            for (int d = 1; d < 64; d <<= 1) {
                const float ov = __shfl_xor(mv, d);
                const int   oi = __shfl_xor(mi, d);
                if (ov < mv || (ov == mv && oi < mi)) { mv = ov; mi = oi; }
            }
            if (r < nr) {
                const int row = rowss[r] & 0x7FFFFFFF;
                const int old = qidx[row];
                if (mi != old) {                  // winner flipped: patch qidx/z_q/hist
                    const int b2 = row >> 12, t2 = row & (T_DIM - 1);
                    const float4 ev = *(const float4*)(embed + (size_t)mi * D_DIM + ll * 4);
                    float* op = out + (size_t)b2 * (D_DIM * T_DIM) + t2;
                    op[(size_t)(ll * 4 + 0) * T_DIM] = ev.x;
                    op[(size_t)(ll * 4 + 1) * T_DIM] = ev.y;
                    op[(size_t)(ll * 4 + 2) * T_DIM] = ev.z;
                    op[(size_t)(ll * 4 + 3) * T_DIM] = ev.w;
                    if (ll == 0) {
                        qidx[row] = mi;
                        atomicAdd(&hist[mi], 1);
                        atomicAdd(&hist[old], -1);
                    }
                }
                if (ll == 0) atomicAdd(loss_sum, mv - bestd[base + r]);
            }
        }
    }

    // ---- fused finalize: last block computes entropy + writes scalar outputs ----
    __threadfence();
    if (tid == 0) {
        const int old = atomicAdd(donecnt, 1);
        amlast = (old == (int)gridDim.x - 1) ? 1 : 0;
    }
    __syncthreads();
    if (amlast) {
        float acc = 0.f;
        for (int i = tid; i < K_NUM; i += 256) {
            const int h = __hip_atomic_load(&hist[i], __ATOMIC_RELAXED,
                                            __HIP_MEMORY_SCOPE_AGENT);
            const float p = (float)h * (1.f / (float)N_TOT);
            acc += p * logf(p + 1e-10f);
        }
        #pragma unroll
        for (int off = 32; off; off >>= 1) acc += __shfl_down(acc, off);
        __shared__ float ls[4];
        if ((tid & 63) == 0) ls[tid >> 6] = acc;
        __syncthreads();
        if (tid == 0) {
            const float H = -(ls[0] + ls[1] + ls[2] + ls[3]);
            const float L = __hip_atomic_load(loss_sum, __ATOMIC_RELAXED,
                                              __HIP_MEMORY_SCOPE_AGENT);
            const size_t base = (size_t)N_TOT * D_DIM;   // 16777216
            out[base] = 1.25f * L * (1.f / 16777216.f);
            const float kld = (float)(6.931471805599453 * 4096.0);  // log(1024)*T
            #pragma unroll
            for (int i = 0; i < 16; ++i) out[base + 1 + i] = kld;
            out[base + 17] = expf(H);
        }
    }
}

extern "C" void kernel_launch(void* const* d_in, const int* in_sizes, int n_in,
                              void* d_out, int out_size, void* d_ws, size_t ws_size,
                              hipStream_t stream)
{
    const float* x     = (const float*)d_in[0];   // (16, 256, 4096) f32
    const float* embed = (const float*)d_in[1];   // (1024, 256) f32
    float* out = (float*)d_out;

    char* ws = (char*)d_ws;
    int*   flagcnt  = (int*)(ws + WS_FLAGCNT);
    float* loss_sum = (float*)(ws + WS_LOSS);
    int*   donecnt  = (int*)(ws + WS_DONE);
    int*   hist     = (int*)(ws + WS_HIST);
    float* e2       = (float*)(ws + WS_E2);
    int*   qidx     = (int*)(ws + WS_QIDX);
    int*   flaglist = (int*)(ws + WS_FLAGLIST);
    float* bestd    = (float*)(ws + WS_BESTD);
    unsigned char* eswz = (unsigned char*)(ws + WS_ESWZ);
    float4* eT4     = (float4*)(ws + WS_ET4);

    // eT4 needs 1 MB beyond eswz; fall back to direct-embed path if ws too small
    const int useET = (ws_size >= (size_t)WS_XROWS_ET + 2048) ? 1 : 0;
    const size_t xrows_off = useET ? (size_t)WS_XROWS_ET : (size_t)WS_XROWS_NOET;
    float* xrows = (float*)(ws + xrows_off);

    int cap = 0;
    if (ws_size > xrows_off + 1024) {
        size_t c = (ws_size - xrows_off) / 1024;
        cap = (c > (size_t)N_TOT) ? N_TOT : (int)c;
    }

    prep_kernel<<<128, 256, 0, stream>>>(embed, eswz, e2, eT4, useET, (int*)ws);
    argmin_mfma_kernel<<<N_TOT / 128, 256, 0, stream>>>(x, eswz, e2, embed, qidx,
                                                        flagcnt, flaglist, bestd, xrows,
                                                        out, hist, loss_sum, cap);
    cleanup_kernel<<<512, 256, 0, stream>>>(x, xrows, embed, eT4, useET, e2,
                                            flagcnt, flaglist, qidx, bestd,
                                            loss_sum, out, hist, donecnt);
}